// Round 1
// baseline (1027.475 us; speedup 1.0000x reference)
//
#include <hip/hip_runtime.h>
#include <cmath>

// All harness inputs/outputs are float32 (per reference dtypes).
// Internally we cast GEMM operands to bf16 (u16 bits) for MFMA.
typedef __bf16 bf16x8 __attribute__((ext_vector_type(8)));
typedef float f32x4 __attribute__((ext_vector_type(4)));

__device__ __forceinline__ float b2f(unsigned short u) {
  union { unsigned int i; float f; } v;
  v.i = ((unsigned int)u) << 16;
  return v.f;
}
__device__ __forceinline__ unsigned short f2b(float f) {
  union { float f; unsigned int i; } v;
  v.f = f;
  unsigned int i = v.i;
  return (unsigned short)((i + 0x7FFFu + ((i >> 16) & 1u)) >> 16);  // RNE
}

// ---------------------------------------------------------------------------
// Cast f32 -> bf16, 4 elements/thread.  n divisible by 1024.
// ---------------------------------------------------------------------------
__global__ __launch_bounds__(256) void k_cast(const float* __restrict__ src,
                                              unsigned short* __restrict__ dst,
                                              int n4) {
  int gid = blockIdx.x * 256 + threadIdx.x;
  if (gid >= n4) return;
  float4 v = *(const float4*)(src + (long)gid * 4);
  uint2 r;
  r.x = (unsigned int)f2b(v.x) | ((unsigned int)f2b(v.y) << 16);
  r.y = (unsigned int)f2b(v.z) | ((unsigned int)f2b(v.w) << 16);
  *(uint2*)(dst + (long)gid * 4) = r;
}

// ---------------------------------------------------------------------------
// pool (mean over 16) + gelu(pooled).  single: (16384,768) f32.
// Outputs bf16.  grid = 1024*192/256 = 768 blocks.
// ---------------------------------------------------------------------------
__global__ __launch_bounds__(256) void k_pool(const float* __restrict__ single,
                                              unsigned short* __restrict__ pooled,
                                              unsigned short* __restrict__ gpool) {
  int gid = blockIdx.x * 256 + threadIdx.x;
  int n = gid / 192;
  int dq = (gid - n * 192) * 4;
  const float* src = single + (long)n * (16 * 768) + dq;
  float s0 = 0.f, s1 = 0.f, s2 = 0.f, s3 = 0.f;
#pragma unroll
  for (int t = 0; t < 16; t++) {
    float4 u = *(const float4*)(src + t * 768);
    s0 += u.x; s1 += u.y; s2 += u.z; s3 += u.w;
  }
  float p0 = s0 * 0.0625f, p1 = s1 * 0.0625f, p2 = s2 * 0.0625f, p3 = s3 * 0.0625f;
  const float inv_sqrt2 = 0.70710678118654752f;
  float g0 = 0.5f * p0 * (1.f + erff(p0 * inv_sqrt2));
  float g1 = 0.5f * p1 * (1.f + erff(p1 * inv_sqrt2));
  float g2 = 0.5f * p2 * (1.f + erff(p2 * inv_sqrt2));
  float g3 = 0.5f * p3 * (1.f + erff(p3 * inv_sqrt2));
  long o = (long)n * 768 + dq;
  uint2 rp, rg;
  rp.x = (unsigned int)f2b(p0) | ((unsigned int)f2b(p1) << 16);
  rp.y = (unsigned int)f2b(p2) | ((unsigned int)f2b(p3) << 16);
  rg.x = (unsigned int)f2b(g0) | ((unsigned int)f2b(g1) << 16);
  rg.y = (unsigned int)f2b(g2) | ((unsigned int)f2b(g3) << 16);
  *(uint2*)(pooled + o) = rp;
  *(uint2*)(gpool + o) = rg;
}

// ---------------------------------------------------------------------------
// Generic MFMA GEMM: C = A(M x K) . B(N x K)^T, bf16 inputs, templated
// epilogue receives (m, n, batch, value_f32).  64x64 tile / block, 4 waves,
// 16x16x32 MFMA.  M,N multiples of 64; K multiple of 32.
// ---------------------------------------------------------------------------
template <class Epi>
__global__ __launch_bounds__(256) void gemm_bt(const unsigned short* __restrict__ A,
                                               const unsigned short* __restrict__ B,
                                               int K, long sA, long sB, Epi epi) {
  __shared__ __align__(16) unsigned short As[64][40];  // pad 40: conflict-free b128
  __shared__ __align__(16) unsigned short Bs[64][40];
  const int tid = threadIdx.x;
  const int lane = tid & 63;
  const int wave = tid >> 6;
  const int wm = wave >> 1;
  const int wn = wave & 1;
  const int z = blockIdx.z;
  const unsigned short* Ab = A + (long)z * sA;
  const unsigned short* Bb = B + (long)z * sB;
  const int m0 = blockIdx.x * 64;
  const int n0 = blockIdx.y * 64;
  const int lrow = tid >> 2;          // 0..63
  const int lcol = (tid & 3) * 8;     // 0,8,16,24
  const int frow = lane & 15;
  const int fk = (lane >> 4) * 8;

  f32x4 zero = {0.f, 0.f, 0.f, 0.f};
  f32x4 acc00 = zero, acc01 = zero, acc10 = zero, acc11 = zero;

  for (int k0 = 0; k0 < K; k0 += 32) {
    *(uint4*)(&As[lrow][lcol]) = *(const uint4*)(Ab + (long)(m0 + lrow) * K + k0 + lcol);
    *(uint4*)(&Bs[lrow][lcol]) = *(const uint4*)(Bb + (long)(n0 + lrow) * K + k0 + lcol);
    __syncthreads();
    bf16x8 a0 = *(const bf16x8*)(&As[wm * 32 + frow][fk]);
    bf16x8 a1 = *(const bf16x8*)(&As[wm * 32 + 16 + frow][fk]);
    bf16x8 b0 = *(const bf16x8*)(&Bs[wn * 32 + frow][fk]);
    bf16x8 b1 = *(const bf16x8*)(&Bs[wn * 32 + 16 + frow][fk]);
    acc00 = __builtin_amdgcn_mfma_f32_16x16x32_bf16(a0, b0, acc00, 0, 0, 0);
    acc01 = __builtin_amdgcn_mfma_f32_16x16x32_bf16(a0, b1, acc01, 0, 0, 0);
    acc10 = __builtin_amdgcn_mfma_f32_16x16x32_bf16(a1, b0, acc10, 0, 0, 0);
    acc11 = __builtin_amdgcn_mfma_f32_16x16x32_bf16(a1, b1, acc11, 0, 0, 0);
    __syncthreads();
  }
  // C/D layout: col = lane&15, row = (lane>>4)*4 + reg  [m89/m91 verified]
  const int em = m0 + wm * 32 + (lane >> 4) * 4;
  const int en = n0 + wn * 32 + (lane & 15);
#pragma unroll
  for (int r = 0; r < 4; r++) {
    epi(em + r,      en,      z, acc00[r]);
    epi(em + r,      en + 16, z, acc01[r]);
    epi(em + 16 + r, en,      z, acc10[r]);
    epi(em + 16 + r, en + 16, z, acc11[r]);
  }
}

// --- epilogues --------------------------------------------------------------
// qk GEMM: n in [0,8192).  n<4096 -> q head h=n>>7, d=n&127; else k.
// Also store biased copies (q+q_bias, k+k_bias) for the rel GEMMs.
// Layouts: q/k/qb/kb as [h][i][d] bf16.  bias is f32 flat [2][32][128]==[n].
struct EpiQK {
  unsigned short* q; unsigned short* k; unsigned short* qb; unsigned short* kb;
  const float* bias;
  __device__ void operator()(int m, int n, int z, float v) const {
    int co = n & 4095;
    int h = co >> 7, d = co & 127;
    long o = ((long)h * 1024 + m) * 128 + d;
    float bv = bias[n];
    if (n < 4096) { q[o] = f2b(v); qb[o] = f2b(v + bv); }
    else          { k[o] = f2b(v); kb[o] = f2b(v + bv); }
  }
};
// rel_enc GEMM: store [hs][p][d] bf16, + b_rel (f32).
struct EpiRel {
  unsigned short* rel; const float* brel;
  __device__ void operator()(int m, int n, int z, float v) const {
    int h = n >> 7, d = n & 127;
    rel[((long)h * 2048 + m) * 128 + d] = f2b(v + brel[n]);
  }
};
// outer GEMM: n<128 -> outer_q (f32), else outer_k.
struct EpiOuter {
  float* oq; float* ok;
  __device__ void operator()(int m, int n, int z, float v) const {
    if (n < 128) oq[(long)m * 128 + n] = v;
    else         ok[(long)m * 128 + (n - 128)] = v;
  }
};
// sim chunk: batch z = head, m = i_local in [0,256).  S0c[i_local][h][j].
struct EpiSimC {
  unsigned short* S;
  __device__ void operator()(int m, int n, int z, float v) const {
    S[((long)m * 32 + z) * 1024 + n] = f2b(v);
  }
};
// rel_q chunk, NATURAL layout: Rq[hs][i_local][pc].  Coalesced (n contiguous).
struct EpiRqC {
  unsigned short* R;
  __device__ void operator()(int m, int n, int z, float v) const {
    R[((long)z * 256 + m) * 1024 + n] = f2b(v);
  }
};
// rel_k chunk, SWAPPED-operand GEMM (A = rel_enc rows, B = kb), so natural
// layout is Rk[hs][pc_local][j] with j contiguous -> coalesced gather later.
struct EpiRkC {
  unsigned short* R;
  __device__ void operator()(int m, int n, int z, float v) const {
    R[((long)z * 320 + m) * 1024 + n] = f2b(v);
  }
};

// ---------------------------------------------------------------------------
// Final (per i-chunk of 256): build S[h][j] = S0 + 0.5*(gather(Rq)+gather(Rk))
// in LDS, then out[i][j][c] = sum_h S[h][j]*w_pair[c][h] + oq[i][c] + ok[j][c]
// + b_pair[c].  One K=32 MFMA per 16j x 16c tile.  out is f32.
//
// Relative-shift inverse (bijection, scatter code verified previously):
//   t = 32*j + h  ->  hs = (t+18431) % 33, ps = (t+18431) / 33
//   valid iff hs < 32 (ps always lands in the cropped [544,1568) window).
// rel_q term at (i,j,h) = Rq[hs1(j,h)][i-i0][ps1(j,h)-544]
// rel_k term at (i,j,h) = Rk[hs2(i,h)][ps2(i,h)-ps_lo][j]   (hs2,ps2 dep. on h only)
// ---------------------------------------------------------------------------
__global__ __launch_bounds__(256) void k_final2(
    const unsigned short* __restrict__ S0,   // [256][32][1024]
    const unsigned short* __restrict__ Rq,   // [32][256][1024]
    const unsigned short* __restrict__ Rk,   // [32][320][1024]
    const float* __restrict__ oq,
    const float* __restrict__ okf,
    const float* __restrict__ wp,
    const float* __restrict__ bp,
    float* __restrict__ out,
    int i0, int ps_lo) {
  __shared__ __align__(16) unsigned short sl[32][72];    // combined S tile [h][j]
  __shared__ __align__(16) unsigned short rq_l[32][72];  // Rq window [hs][pc-pcA]
  const int il = blockIdx.y;          // local i in [0,256)
  const int i  = i0 + il;
  const int j0 = blockIdx.x * 64;
  const int t  = threadIdx.x;
  const int h  = t >> 3;
  const int jj = (t & 7) * 8;

  // --- stage Rq window: need pc in [p0-544, p0-544+63]; align down to 8 for
  // 16B loads -> window [pcA, pcA+72), 32 rows x 9 uint4 = 288 loads.
  const int p0  = (j0 * 32 + 18431) / 33;   // min ps over block (j=j0,h=0)
  const int pcA = (p0 - 544) & ~7;          // in [8,944]; pcA+71 <= 1015 < 1024
  for (int c = t; c < 288; c += 256) {
    int row = c / 9;
    int off = (c - row * 9) * 8;
    *(uint4*)(&rq_l[row][off]) =
        *(const uint4*)(Rq + ((long)row * 256 + il) * 1024 + pcA + off);
  }
  // --- S0 and Rk for this thread's own (h, jj..jj+7) elements: registers.
  uint4 s0v = *(const uint4*)(S0 + ((long)il * 32 + h) * 1024 + j0 + jj);
  const int t2  = i * 32 + h + 18431;
  const int ps2 = t2 / 33;
  const int hs2 = t2 - ps2 * 33;
  uint4 rkv = {0u, 0u, 0u, 0u};
  if (hs2 < 32)
    rkv = *(const uint4*)(Rk + ((long)hs2 * 320 + (ps2 - ps_lo)) * 1024 + j0 + jj);
  __syncthreads();
  // --- combine into sl (f32 math, one bf16 round)
  const unsigned short* s0p = (const unsigned short*)&s0v;
  const unsigned short* rkp = (const unsigned short*)&rkv;
#pragma unroll
  for (int e = 0; e < 8; e++) {
    const int j  = jj + e;
    const int t1 = (j0 + j) * 32 + h + 18431;
    const int ps1 = t1 / 33;
    const int hs1 = t1 - ps1 * 33;
    float rq = (hs1 < 32) ? b2f(rq_l[hs1][ps1 - 544 - pcA]) : 0.f;
    sl[h][j] = f2b(b2f(s0p[e]) + 0.5f * (rq + b2f(rkp[e])));
  }
  __syncthreads();
  // --- MFMA part (unchanged)
  const int lane = t & 63;
  const int wv = t >> 6;
  const int jbase = wv * 16;
  const int r16 = lane & 15;
  const int kq = lane >> 4;
  union { unsigned short u[8]; bf16x8 v; } af;
#pragma unroll
  for (int s = 0; s < 8; s++) af.u[s] = sl[kq * 8 + s][jbase + r16];  // A[j][h]
#pragma unroll
  for (int ct = 0; ct < 8; ct++) {
    const int c0 = ct * 16;
    union { unsigned short u[8]; bf16x8 v; } bfr;
#pragma unroll
    for (int s = 0; s < 8; s++) bfr.u[s] = f2b(wp[(c0 + r16) * 32 + kq * 8 + s]);  // B[c][h]
    f32x4 acc = {0.f, 0.f, 0.f, 0.f};
    acc = __builtin_amdgcn_mfma_f32_16x16x32_bf16(af.v, bfr.v, acc, 0, 0, 0);
    const int cD = c0 + r16;
    const float addc = oq[i * 128 + cD] + bp[cD];
#pragma unroll
    for (int r = 0; r < 4; r++) {
      const int j = j0 + jbase + kq * 4 + r;
      out[(long)i * 131072 + j * 128 + cD] = acc[r] + addc + okf[j * 128 + cD];
    }
  }
}

// ---------------------------------------------------------------------------
extern "C" void kernel_launch(void* const* d_in, const int* in_sizes, int n_in,
                              void* d_out, int out_size, void* d_ws, size_t ws_size,
                              hipStream_t stream) {
  (void)in_sizes; (void)n_in; (void)out_size; (void)ws_size;
  const float* single  = (const float*)d_in[0];
  const float* relfeat = (const float*)d_in[1];
  const float* w_qk    = (const float*)d_in[2];
  const float* w_outer = (const float*)d_in[3];
  const float* w_pair  = (const float*)d_in[4];
  const float* b_pair  = (const float*)d_in[5];
  const float* w_rel   = (const float*)d_in[6];
  const float* b_rel   = (const float*)d_in[7];
  const float* qk_bias = (const float*)d_in[8];
  float* out = (float*)d_out;
  char* ws = (char*)d_ws;

  // workspace layout (bytes); total ~131.5 MiB (< 144 MiB proven available)
  unsigned short* pooled  = (unsigned short*)(ws + 0);          // 1024x768 bf16
  unsigned short* gpool   = (unsigned short*)(ws + 1572864);    // 1024x768 bf16
  unsigned short* q       = (unsigned short*)(ws + 3145728);    // [32][1024][128]
  unsigned short* k       = (unsigned short*)(ws + 11534336);
  unsigned short* qb      = (unsigned short*)(ws + 19922944);
  unsigned short* kb      = (unsigned short*)(ws + 28311552);
  unsigned short* rel     = (unsigned short*)(ws + 36700160);   // [32][2048][128]
  float*          oq      = (float*)(ws + 53477376);            // 1024x128 f32
  float*          okf     = (float*)(ws + 54001664);            // 1024x128 f32
  unsigned short* wqk_b   = (unsigned short*)(ws + 54525952);   // 8192x768 bf16
  unsigned short* wrel_b  = (unsigned short*)(ws + 67108864);   // 4096x768 bf16
  unsigned short* rfeat_b = (unsigned short*)(ws + 73400320);   // 2048x768 bf16
  unsigned short* wout_b  = (unsigned short*)(ws + 76546048);   // 256x768 bf16
  unsigned short* S0c     = (unsigned short*)(ws + 76939264);   // [256][32][1024]
  unsigned short* Rqc     = (unsigned short*)(ws + 93716480);   // [32][256][1024]
  unsigned short* Rkc     = (unsigned short*)(ws + 110493696);  // [32][320][1024]

  // f32 -> bf16 casts for GEMM operands
  k_cast<<<6144, 256, 0, stream>>>(w_qk,    wqk_b,   1572864);
  k_cast<<<3072, 256, 0, stream>>>(w_rel,   wrel_b,   786432);
  k_cast<<<1536, 256, 0, stream>>>(relfeat, rfeat_b,  393216);
  k_cast<<< 192, 256, 0, stream>>>(w_outer, wout_b,    49152);

  k_pool<<<768, 256, 0, stream>>>(single, pooled, gpool);
  // qk = pooled @ w_qk^T   (M=1024, N=8192, K=768)
  gemm_bt<<<dim3(16, 128, 1), 256, 0, stream>>>(pooled, wqk_b, 768, 0L, 0L,
                                                EpiQK{q, k, qb, kb, qk_bias});
  // rel_enc = rel_pos_feats @ w_rel^T + b_rel   (M=2048, N=4096, K=768)
  gemm_bt<<<dim3(32, 64, 1), 256, 0, stream>>>(rfeat_b, wrel_b, 768, 0L, 0L,
                                               EpiRel{rel, b_rel});
  // outer = gelu(pooled) @ w_outer^T   (M=1024, N=256, K=768)
  gemm_bt<<<dim3(16, 4, 1), 256, 0, stream>>>(gpool, wout_b, 768, 0L, 0L,
                                              EpiOuter{oq, okf});

  // --- 4 i-chunks of 256: sim / rel_q / rel_k into chunk buffers (all
  // coalesced natural-layout stores, no RMW), then fused gather + final.
  for (int ic = 0; ic < 4; ic++) {
    const int i0 = ic * 256;
    const int ps_lo = (32 * i0 + 18431) / 33;  // min ps2 over chunk; width <=250
    // sim: per-head q.k^T  (32 batches, M=256 local rows, N=1024, K=128)
    gemm_bt<<<dim3(4, 16, 32), 256, 0, stream>>>(q + (long)i0 * 128, k, 128,
                                                 131072L, 131072L, EpiSimC{S0c});
    // rel_q: qb_chunk . rel_enc[544:1568]^T -> Rq[hs][i_local][pc]
    gemm_bt<<<dim3(4, 16, 32), 256, 0, stream>>>(qb + (long)i0 * 128, rel + 69632,
                                                 128, 131072L, 262144L, EpiRqC{Rqc});
    // rel_k SWAPPED: rel_enc[ps_lo:ps_lo+320] . kb^T -> Rk[hs][pc_local][j]
    gemm_bt<<<dim3(5, 16, 32), 256, 0, stream>>>(rel + (long)ps_lo * 128, kb, 128,
                                                 262144L, 131072L, EpiRkC{Rkc});
    // final: combine + pairwise + outer_sum -> out rows [i0, i0+256)
    k_final2<<<dim3(16, 256), 256, 0, stream>>>(S0c, Rqc, Rkc, oq, okf,
                                                w_pair, b_pair, out, i0, ps_lo);
  }
}

// Round 2
// 989.870 us; speedup vs baseline: 1.0380x; 1.0380x over previous
//
#include <hip/hip_runtime.h>
#include <cmath>

// All harness inputs/outputs are float32 (per reference dtypes).
// Internally we cast GEMM operands to bf16 (u16 bits) for MFMA.
typedef __bf16 bf16x8 __attribute__((ext_vector_type(8)));
typedef float f32x4 __attribute__((ext_vector_type(4)));

__device__ __forceinline__ float b2f(unsigned short u) {
  union { unsigned int i; float f; } v;
  v.i = ((unsigned int)u) << 16;
  return v.f;
}
__device__ __forceinline__ unsigned short f2b(float f) {
  union { float f; unsigned int i; } v;
  v.f = f;
  unsigned int i = v.i;
  return (unsigned short)((i + 0x7FFFu + ((i >> 16) & 1u)) >> 16);  // RNE
}

// async global->LDS, 16B per lane.  lds base must be wave-uniform (m104).
__device__ __forceinline__ void gld_lds16(const unsigned short* g, unsigned short* l) {
  __builtin_amdgcn_global_load_lds(
      (__attribute__((address_space(1))) void*)(void*)(g),
      (__attribute__((address_space(3))) void*)(l), 16, 0, 0);
}

// ---------------------------------------------------------------------------
// All four f32->bf16 weight casts in one dispatch.  4 elems/thread.
// sizes (float4 groups): wqk 1572864 | wrel 786432 | rfeat 393216 | wout 49152
// grid = 2801664/256 = 10944 blocks.
// ---------------------------------------------------------------------------
__global__ __launch_bounds__(256) void k_cast_all(
    const float* __restrict__ s0, unsigned short* __restrict__ d0,
    const float* __restrict__ s1, unsigned short* __restrict__ d1,
    const float* __restrict__ s2, unsigned short* __restrict__ d2,
    const float* __restrict__ s3, unsigned short* __restrict__ d3) {
  int gid = blockIdx.x * 256 + threadIdx.x;
  const float* s; unsigned short* d;
  if (gid < 1572864)      { s = s0; d = d0; }
  else if (gid < 2359296) { s = s1; d = d1; gid -= 1572864; }
  else if (gid < 2752512) { s = s2; d = d2; gid -= 2359296; }
  else                    { s = s3; d = d3; gid -= 2752512; }
  float4 v = *(const float4*)(s + (long)gid * 4);
  uint2 r;
  r.x = (unsigned int)f2b(v.x) | ((unsigned int)f2b(v.y) << 16);
  r.y = (unsigned int)f2b(v.z) | ((unsigned int)f2b(v.w) << 16);
  *(uint2*)(d + (long)gid * 4) = r;
}

// ---------------------------------------------------------------------------
// pool (mean over 16) + gelu(pooled).  single: (16384,768) f32.
// Outputs bf16.  grid = 1024*192/256 = 768 blocks.
// ---------------------------------------------------------------------------
__global__ __launch_bounds__(256) void k_pool(const float* __restrict__ single,
                                              unsigned short* __restrict__ pooled,
                                              unsigned short* __restrict__ gpool) {
  int gid = blockIdx.x * 256 + threadIdx.x;
  int n = gid / 192;
  int dq = (gid - n * 192) * 4;
  const float* src = single + (long)n * (16 * 768) + dq;
  float s0 = 0.f, s1 = 0.f, s2 = 0.f, s3 = 0.f;
#pragma unroll
  for (int t = 0; t < 16; t++) {
    float4 u = *(const float4*)(src + t * 768);
    s0 += u.x; s1 += u.y; s2 += u.z; s3 += u.w;
  }
  float p0 = s0 * 0.0625f, p1 = s1 * 0.0625f, p2 = s2 * 0.0625f, p3 = s3 * 0.0625f;
  const float inv_sqrt2 = 0.70710678118654752f;
  float g0 = 0.5f * p0 * (1.f + erff(p0 * inv_sqrt2));
  float g1 = 0.5f * p1 * (1.f + erff(p1 * inv_sqrt2));
  float g2 = 0.5f * p2 * (1.f + erff(p2 * inv_sqrt2));
  float g3 = 0.5f * p3 * (1.f + erff(p3 * inv_sqrt2));
  long o = (long)n * 768 + dq;
  uint2 rp, rg;
  rp.x = (unsigned int)f2b(p0) | ((unsigned int)f2b(p1) << 16);
  rp.y = (unsigned int)f2b(p2) | ((unsigned int)f2b(p3) << 16);
  rg.x = (unsigned int)f2b(g0) | ((unsigned int)f2b(g1) << 16);
  rg.y = (unsigned int)f2b(g2) | ((unsigned int)f2b(g3) << 16);
  *(uint2*)(pooled + o) = rp;
  *(uint2*)(gpool + o) = rg;
}

// ---------------------------------------------------------------------------
// m97-structure MFMA GEMM: C = A(M x K) . B(N x K)^T, bf16 in, f32 epilogue.
// 128x128 tile / block, BK=32, 4 waves (2x2), 4x4 fragments/wave, 16x16x32
// MFMA, linear LDS + global_load_lds width 16.  M,N mult of 128; K mult of 32.
// ---------------------------------------------------------------------------
template <class Epi>
__global__ __launch_bounds__(256) void gemm_bt(const unsigned short* __restrict__ A,
                                               const unsigned short* __restrict__ B,
                                               int K, long sA, long sB, Epi epi) {
  __shared__ __align__(16) unsigned short As[128 * 32];  // linear: row*32 + k
  __shared__ __align__(16) unsigned short Bs[128 * 32];
  const int tid = threadIdx.x;
  const int lane = tid & 63;
  const int w = tid >> 6;
  const int wm = w >> 1;
  const int wn = w & 1;
  const int z = blockIdx.z;
  const unsigned short* Ab = A + (long)z * sA;
  const unsigned short* Bb = B + (long)z * sB;
  const int m0 = blockIdx.x * 128;
  const int n0 = blockIdx.y * 128;
  const int frow = lane & 15;
  const int fk = (lane >> 4) * 8;
  // staging geometry: 512 chunks of 16B per operand; chunk c = t*256 + tid;
  // row = c>>2, kcol = (c&3)*8.  LDS dest = linear c*16 bytes (wave-uniform
  // base (t*256+w*64)*16 + lane*16).
  const int r0 = tid >> 2;            // row for t=0 chunk
  const int c0 = (tid & 3) * 8;
  f32x4 acc[4][4];
#pragma unroll
  for (int fm = 0; fm < 4; fm++)
#pragma unroll
    for (int fn = 0; fn < 4; fn++) acc[fm][fn] = (f32x4){0.f, 0.f, 0.f, 0.f};

  for (int k0 = 0; k0 < K; k0 += 32) {
    gld_lds16(Ab + (long)(m0 + r0) * K + k0 + c0,       &As[(w * 64) * 8]);
    gld_lds16(Ab + (long)(m0 + 64 + r0) * K + k0 + c0,  &As[(256 + w * 64) * 8]);
    gld_lds16(Bb + (long)(n0 + r0) * K + k0 + c0,       &Bs[(w * 64) * 8]);
    gld_lds16(Bb + (long)(n0 + 64 + r0) * K + k0 + c0,  &Bs[(256 + w * 64) * 8]);
    __syncthreads();
    bf16x8 a[4], b[4];
#pragma unroll
    for (int f = 0; f < 4; f++) {
      a[f] = *(const bf16x8*)&As[(wm * 64 + f * 16 + frow) * 32 + fk];
      b[f] = *(const bf16x8*)&Bs[(wn * 64 + f * 16 + frow) * 32 + fk];
    }
#pragma unroll
    for (int fm = 0; fm < 4; fm++)
#pragma unroll
      for (int fn = 0; fn < 4; fn++)
        acc[fm][fn] = __builtin_amdgcn_mfma_f32_16x16x32_bf16(a[fm], b[fn], acc[fm][fn], 0, 0, 0);
    __syncthreads();
  }
  // C/D layout: col = lane&15, row = (lane>>4)*4 + reg  [m89/m91 verified]
  const int er = (lane >> 4) * 4;
  const int ec = lane & 15;
#pragma unroll
  for (int fm = 0; fm < 4; fm++)
#pragma unroll
    for (int fn = 0; fn < 4; fn++)
#pragma unroll
      for (int r = 0; r < 4; r++)
        epi(m0 + wm * 64 + fm * 16 + er + r, n0 + wn * 64 + fn * 16 + ec, z, acc[fm][fn][r]);
}

// --- epilogues --------------------------------------------------------------
// qk GEMM: n in [0,8192).  n<4096 -> q head h=n>>7, d=n&127; else k.
// Also store biased copies (q+q_bias, k+k_bias) for the rel GEMMs.
// Layouts: q/k/qb/kb as [h][i][d] bf16.  bias is f32 flat [2][32][128]==[n].
struct EpiQK {
  unsigned short* q; unsigned short* k; unsigned short* qb; unsigned short* kb;
  const float* bias;
  __device__ void operator()(int m, int n, int z, float v) const {
    int co = n & 4095;
    int h = co >> 7, d = co & 127;
    long o = ((long)h * 1024 + m) * 128 + d;
    float bv = bias[n];
    if (n < 4096) { q[o] = f2b(v); qb[o] = f2b(v + bv); }
    else          { k[o] = f2b(v); kb[o] = f2b(v + bv); }
  }
};
// rel_enc GEMM: store [hs][p][d] bf16, + b_rel (f32).
struct EpiRel {
  unsigned short* rel; const float* brel;
  __device__ void operator()(int m, int n, int z, float v) const {
    int h = n >> 7, d = n & 127;
    rel[((long)h * 2048 + m) * 128 + d] = f2b(v + brel[n]);
  }
};
// outer GEMM: n<128 -> outer_q (f32), else outer_k.
struct EpiOuter {
  float* oq; float* ok;
  __device__ void operator()(int m, int n, int z, float v) const {
    if (n < 128) oq[(long)m * 128 + n] = v;
    else         ok[(long)m * 128 + (n - 128)] = v;
  }
};
// sim: batch z = head, m = i_local.  S0[i_local][h][j].
struct EpiSimC {
  unsigned short* S;
  __device__ void operator()(int m, int n, int z, float v) const {
    S[((long)m * 32 + z) * 1024 + n] = f2b(v);
  }
};
// rel_q, NATURAL layout: Rq[hs][i_local][pc]  (n = pc contiguous).
struct EpiRqC {
  unsigned short* R; int CH;
  __device__ void operator()(int m, int n, int z, float v) const {
    R[((long)z * CH + m) * 1024 + n] = f2b(v);
  }
};
// rel_k, SWAPPED-operand GEMM (A = rel_enc rows, B = kb): Rk[hs][pc_local][j].
struct EpiRkC {
  unsigned short* R; int RR;
  __device__ void operator()(int m, int n, int z, float v) const {
    R[((long)z * RR + m) * 1024 + n] = f2b(v);
  }
};

// ---------------------------------------------------------------------------
// Final: build S[h][j] = S0 + 0.5*(gather(Rq)+gather(Rk)) in LDS, then
// out[i][j][c] = sum_h S[h][j]*w_pair[c][h] + oq[i][c] + ok[j][c] + b_pair[c].
// One K=32 MFMA per 16j x 16c tile.  out is f32.
//
// Relative-shift inverse (bijection):
//   t = 32*j + h  ->  hs = (t+18431) % 33, ps = (t+18431) / 33, valid iff hs<32.
// rel_q term at (i,j,h) = Rq[hs1(j,h)][i-i0][ps1(j,h)-544]
// rel_k term at (i,j,h) = Rk[hs2(i,h)][ps2(i,h)-ps_lo][j]   (dep. on h only)
// ---------------------------------------------------------------------------
__global__ __launch_bounds__(256) void k_final2(
    const unsigned short* __restrict__ S0,   // [CH][32][1024]
    const unsigned short* __restrict__ Rq,   // [32][CH][1024]
    const unsigned short* __restrict__ Rk,   // [32][RR][1024]
    const float* __restrict__ oq,
    const float* __restrict__ okf,
    const float* __restrict__ wp,
    const float* __restrict__ bp,
    float* __restrict__ out,
    int i0, int ps_lo, int CH, int RR) {
  __shared__ __align__(16) unsigned short sl[32][72];    // combined S tile [h][j]
  __shared__ __align__(16) unsigned short rq_l[32][72];  // Rq window [hs][pc-pcA]
  const int il = blockIdx.y;          // local i in [0,CH)
  const int i  = i0 + il;
  const int j0 = blockIdx.x * 64;
  const int t  = threadIdx.x;
  const int h  = t >> 3;
  const int jj = (t & 7) * 8;

  // --- stage Rq window: pc in [p0-544 .. +~69]; align down to 8 for 16B loads.
  const int p0  = (j0 * 32 + 18431) / 33;   // min ps over block
  const int pcA = (p0 - 544) & ~7;
  for (int c = t; c < 288; c += 256) {
    int row = c / 9;
    int off = (c - row * 9) * 8;
    *(uint4*)(&rq_l[row][off]) =
        *(const uint4*)(Rq + ((long)row * CH + il) * 1024 + pcA + off);
  }
  // --- S0 and Rk for this thread's own (h, jj..jj+7) elements: registers.
  uint4 s0v = *(const uint4*)(S0 + ((long)il * 32 + h) * 1024 + j0 + jj);
  const int t2  = i * 32 + h + 18431;
  const int ps2 = t2 / 33;
  const int hs2 = t2 - ps2 * 33;
  uint4 rkv = {0u, 0u, 0u, 0u};
  if (hs2 < 32)
    rkv = *(const uint4*)(Rk + ((long)hs2 * RR + (ps2 - ps_lo)) * 1024 + j0 + jj);
  __syncthreads();
  // --- combine into sl (f32 math, one bf16 round)
  const unsigned short* s0p = (const unsigned short*)&s0v;
  const unsigned short* rkp = (const unsigned short*)&rkv;
#pragma unroll
  for (int e = 0; e < 8; e++) {
    const int j  = jj + e;
    const int t1 = (j0 + j) * 32 + h + 18431;
    const int ps1 = t1 / 33;
    const int hs1 = t1 - ps1 * 33;
    float rq = (hs1 < 32) ? b2f(rq_l[hs1][ps1 - 544 - pcA]) : 0.f;
    sl[h][j] = f2b(b2f(s0p[e]) + 0.5f * (rq + b2f(rkp[e])));
  }
  __syncthreads();
  // --- MFMA part
  const int lane = t & 63;
  const int wv = t >> 6;
  const int jbase = wv * 16;
  const int r16 = lane & 15;
  const int kq = lane >> 4;
  union { unsigned short u[8]; bf16x8 v; } af;
#pragma unroll
  for (int s = 0; s < 8; s++) af.u[s] = sl[kq * 8 + s][jbase + r16];  // A[j][h]
#pragma unroll
  for (int ct = 0; ct < 8; ct++) {
    const int c0 = ct * 16;
    union { unsigned short u[8]; bf16x8 v; } bfr;
#pragma unroll
    for (int s = 0; s < 8; s++) bfr.u[s] = f2b(wp[(c0 + r16) * 32 + kq * 8 + s]);  // B[c][h]
    f32x4 acc = {0.f, 0.f, 0.f, 0.f};
    acc = __builtin_amdgcn_mfma_f32_16x16x32_bf16(af.v, bfr.v, acc, 0, 0, 0);
    const int cD = c0 + r16;
    const float addc = oq[i * 128 + cD] + bp[cD];
#pragma unroll
    for (int r = 0; r < 4; r++) {
      const int j = j0 + jbase + kq * 4 + r;
      out[(long)i * 131072 + j * 128 + cD] = acc[r] + addc + okf[j * 128 + cD];
    }
  }
}

// ---------------------------------------------------------------------------
extern "C" void kernel_launch(void* const* d_in, const int* in_sizes, int n_in,
                              void* d_out, int out_size, void* d_ws, size_t ws_size,
                              hipStream_t stream) {
  (void)in_sizes; (void)n_in; (void)out_size;
  const float* single  = (const float*)d_in[0];
  const float* relfeat = (const float*)d_in[1];
  const float* w_qk    = (const float*)d_in[2];
  const float* w_outer = (const float*)d_in[3];
  const float* w_pair  = (const float*)d_in[4];
  const float* b_pair  = (const float*)d_in[5];
  const float* w_rel   = (const float*)d_in[6];
  const float* b_rel   = (const float*)d_in[7];
  const float* qk_bias = (const float*)d_in[8];
  float* out = (float*)d_out;
  char* ws = (char*)d_ws;

  // fixed region: ~76.9 MiB
  unsigned short* pooled  = (unsigned short*)(ws + 0);          // 1024x768 bf16
  unsigned short* gpool   = (unsigned short*)(ws + 1572864);
  unsigned short* q       = (unsigned short*)(ws + 3145728);    // [32][1024][128]
  unsigned short* k       = (unsigned short*)(ws + 11534336);
  unsigned short* qb      = (unsigned short*)(ws + 19922944);
  unsigned short* kb      = (unsigned short*)(ws + 28311552);
  unsigned short* rel     = (unsigned short*)(ws + 36700160);   // [32][2048][128]
  float*          oq      = (float*)(ws + 53477376);            // 1024x128 f32
  float*          okf     = (float*)(ws + 54001664);
  unsigned short* wqk_b   = (unsigned short*)(ws + 54525952);   // 8192x768 bf16
  unsigned short* wrel_b  = (unsigned short*)(ws + 67108864);   // 4096x768 bf16
  unsigned short* rfeat_b = (unsigned short*)(ws + 73400320);   // 2048x768 bf16
  unsigned short* wout_b  = (unsigned short*)(ws + 76546048);   // 256x768 bf16

  // chunking: full path (1 chunk of 1024) needs ~278 MiB total; evidence
  // (2^31-byte workspace poison fill) says ws_size = 2 GiB.  Fallback: 4x256.
  int nch, CH, RR;
  if (ws_size >= 280u * 1024u * 1024u) { nch = 1; CH = 1024; RR = 1024; }
  else                                 { nch = 4; CH = 256;  RR = 384;  }
  unsigned short* S0c = (unsigned short*)(ws + 76939264);
  unsigned short* Rqc = S0c + (long)CH * 32 * 1024;
  unsigned short* Rkc = Rqc + (long)CH * 32 * 1024;

  k_cast_all<<<10944, 256, 0, stream>>>(w_qk, wqk_b, w_rel, wrel_b,
                                        relfeat, rfeat_b, w_outer, wout_b);
  k_pool<<<768, 256, 0, stream>>>(single, pooled, gpool);
  // qk = pooled @ w_qk^T   (M=1024, N=8192, K=768)
  gemm_bt<<<dim3(8, 64, 1), 256, 0, stream>>>(pooled, wqk_b, 768, 0L, 0L,
                                              EpiQK{q, k, qb, kb, qk_bias});
  // rel_enc = rel_pos_feats @ w_rel^T + b_rel   (M=2048, N=4096, K=768)
  gemm_bt<<<dim3(16, 32, 1), 256, 0, stream>>>(rfeat_b, wrel_b, 768, 0L, 0L,
                                               EpiRel{rel, b_rel});
  // outer = gelu(pooled) @ w_outer^T   (M=1024, N=256, K=768)
  gemm_bt<<<dim3(8, 2, 1), 256, 0, stream>>>(gpool, wout_b, 768, 0L, 0L,
                                             EpiOuter{oq, okf});

  for (int ic = 0; ic < nch; ic++) {
    const int i0 = ic * CH;
    const int ps_lo = (32 * i0 + 18431) / 33;  // min ps2 over chunk
    // sim: per-head q.k^T  (32 batches, M=CH, N=1024, K=128)
    gemm_bt<<<dim3(CH / 128, 8, 32), 256, 0, stream>>>(q + (long)i0 * 128, k, 128,
                                                       131072L, 131072L, EpiSimC{S0c});
    // rel_q: qb_chunk . rel_enc[544:1568]^T -> Rq[hs][i_local][pc]
    gemm_bt<<<dim3(CH / 128, 8, 32), 256, 0, stream>>>(qb + (long)i0 * 128, rel + 69632,
                                                       128, 131072L, 262144L,
                                                       EpiRqC{Rqc, CH});
    // rel_k SWAPPED: rel_enc[ps_lo:ps_lo+RR] . kb^T -> Rk[hs][pc_local][j]
    gemm_bt<<<dim3(RR / 128, 8, 32), 256, 0, stream>>>(rel + (long)ps_lo * 128, kb, 128,
                                                       262144L, 131072L,
                                                       EpiRkC{Rkc, RR});
    // final: combine + pairwise + outer_sum -> out rows [i0, i0+CH)
    k_final2<<<dim3(16, CH), 256, 0, stream>>>(S0c, Rqc, Rkc, oq, okf,
                                               w_pair, b_pair, out, i0, ps_lo, CH, RR);
  }
}